// Round 1
// baseline (182.145 us; speedup 1.0000x reference)
//
#include <hip/hip_runtime.h>
#include <hip/hip_bf16.h>

// Problem: B=32, C_IN=2048, C=1024, H=W=14, N_CLS=30
// pooled[b,c] = (1/14^3) * sum_h (conv_w @ sum_w f1)[b,c,h] * (sum_w f2)[b,c,h]
// out = pooled @ fc_w^T + fc_b
//
// ws layout:
//   [0, 2MB)   f1mT  ushort(bf16) [512][2048]   rows n = b*16+h (h padded to 16)
//   [2MB,6MB)  cwb   ushort(bf16) [1024][2048]
//   [6MB,8MB)  ym    float [32][16][1024]
//   [8MB,10MB) xm    float [512][1024]

typedef __attribute__((ext_vector_type(8))) short short8;
typedef __attribute__((ext_vector_type(4))) float f32x4;

static __device__ __forceinline__ unsigned short f2bf(float f) {
    union { float f; unsigned u; } v; v.f = f;
    return (unsigned short)((v.u + 0x7FFFu + ((v.u >> 16) & 1u)) >> 16);
}

// ---------------- K1: reductions + casts (memory-bound streamer) -------------
// grid partition: [0,1792) jobA f1-reduce, [1792,2688) jobB f2-reduce,
//                 [2688,4736) jobC conv_w cast
__global__ __launch_bounds__(256) void k1_prep(
    const float* __restrict__ f1, const float* __restrict__ f2,
    const float* __restrict__ cw,
    unsigned short* __restrict__ f1mt, unsigned short* __restrict__ cwb,
    float* __restrict__ ym)
{
    const float inv14 = 1.0f / 14.0f;
    int blk = blockIdx.x;
    if (blk < 1792) {
        // jobA: t = (b*7 + h2)*2048 + i ; reads 28 floats (2 h-rows), writes 2 bf16
        int t = blk * 256 + threadIdx.x;
        int bh = t >> 11;          // b*7 + h2
        int i  = t & 2047;
        int b  = bh / 7;
        int h2 = bh - b * 7;
        const float4* p = (const float4*)(f1 + ((b * 2048 + i) * 196 + h2 * 28));
        float4 v0 = p[0], v1 = p[1], v2 = p[2], v3 = p[3];
        float4 v4 = p[4], v5 = p[5], v6 = p[6];
        float s0 = v0.x+v0.y+v0.z+v0.w + v1.x+v1.y+v1.z+v1.w
                 + v2.x+v2.y+v2.z+v2.w + v3.x+v3.y;
        float s1 = v3.z+v3.w + v4.x+v4.y+v4.z+v4.w
                 + v5.x+v5.y+v5.z+v5.w + v6.x+v6.y+v6.z+v6.w;
        int n = b * 16 + h2 * 2;
        f1mt[n * 2048 + i]       = f2bf(s0 * inv14);
        f1mt[(n + 1) * 2048 + i] = f2bf(s1 * inv14);
        if (h2 == 6) {  // zero-pad h = 14,15
            f1mt[(n + 2) * 2048 + i] = 0;
            f1mt[(n + 3) * 2048 + i] = 0;
        }
    } else if (blk < 2688) {
        // jobB: t = (b*7 + h2)*1024 + c
        int t = (blk - 1792) * 256 + threadIdx.x;
        int bh = t >> 10;
        int c  = t & 1023;
        int b  = bh / 7;
        int h2 = bh - b * 7;
        const float4* p = (const float4*)(f2 + ((b * 1024 + c) * 196 + h2 * 28));
        float4 v0 = p[0], v1 = p[1], v2 = p[2], v3 = p[3];
        float4 v4 = p[4], v5 = p[5], v6 = p[6];
        float s0 = v0.x+v0.y+v0.z+v0.w + v1.x+v1.y+v1.z+v1.w
                 + v2.x+v2.y+v2.z+v2.w + v3.x+v3.y;
        float s1 = v3.z+v3.w + v4.x+v4.y+v4.z+v4.w
                 + v5.x+v5.y+v5.z+v5.w + v6.x+v6.y+v6.z+v6.w;
        float* yp = ym + ((b * 16 + h2 * 2) * 1024 + c);
        yp[0]    = s0 * inv14;
        yp[1024] = s1 * inv14;
        if (h2 == 6) { yp[2048] = 0.0f; yp[3072] = 0.0f; }
    } else {
        // jobC: cast conv_w to bf16, 4 elems/thread
        int t = (blk - 2688) * 256 + threadIdx.x;
        float4 v = *(const float4*)(cw + t * 4);
        ushort4 o;
        o.x = f2bf(v.x); o.y = f2bf(v.y); o.z = f2bf(v.z); o.w = f2bf(v.w);
        *(ushort4*)(cwb + t * 4) = o;
    }
}

// ---------------- K2: bf16 MFMA GEMM  xm[n][c] = (cwb @ f1mT^T)^T -------------
// M=1024 (c), N=512 (n=b*16+h), K=2048.
// 128 blocks (16 ct x 8 nt) x 512 threads. Each wave = one K-chunk of 256 for
// the block's 64x64 tile; cross-wave reduce via LDS atomics.
// NOTE on fragment k-layout: each lane loads 8 CONTIGUOUS k for BOTH A and B at
// k = kchunk + (lane>>4)*8. A and B share the same (lane,j)->k hardware map, so
// any consistent permutation of k leaves sum_k A[m][k]*B[k][n] exact. This makes
// the kernel independent of the undocumented x32 k-interleave.
__global__ __launch_bounds__(512) void k2_gemm(
    const unsigned short* __restrict__ A,   // cwb  [1024][2048]
    const unsigned short* __restrict__ Bm,  // f1mt [512][2048]
    float* __restrict__ xm)                 // [512][1024]
{
    __shared__ float tile[64 * 64];
    int tid = threadIdx.x;
    int w   = tid >> 6;        // k-chunk id 0..7
    int l   = tid & 63;
    int lg  = l >> 4;          // lane k-group
    int lr  = l & 15;          // lane row/col
    int ct  = blockIdx.x >> 3;
    int nt  = blockIdx.x & 7;
    int c0  = ct * 64, n0 = nt * 64;

    // zero the LDS accumulation tile
    #pragma unroll
    for (int q = 0; q < 8; q++) tile[tid * 8 + q] = 0.0f;

    f32x4 acc[4][4];
    #pragma unroll
    for (int mf = 0; mf < 4; mf++)
        #pragma unroll
        for (int nf = 0; nf < 4; nf++)
            acc[mf][nf] = (f32x4){0.f, 0.f, 0.f, 0.f};

    int kbase = w * 256;
    const unsigned short* Ap = A  + (c0 + lr) * 2048 + kbase + lg * 8;
    const unsigned short* Bp = Bm + (n0 + lr) * 2048 + kbase + lg * 8;

    #pragma unroll
    for (int ks = 0; ks < 256; ks += 32) {
        short8 af[4], bb[4];
        #pragma unroll
        for (int mf = 0; mf < 4; mf++)
            af[mf] = *(const short8*)(Ap + mf * 16 * 2048 + ks);
        #pragma unroll
        for (int nf = 0; nf < 4; nf++)
            bb[nf] = *(const short8*)(Bp + nf * 16 * 2048 + ks);
        #pragma unroll
        for (int mf = 0; mf < 4; mf++)
            #pragma unroll
            for (int nf = 0; nf < 4; nf++)
                acc[mf][nf] = __builtin_amdgcn_mfma_f32_16x16x32_bf16(
                    af[mf], bb[nf], acc[mf][nf], 0, 0, 0);
    }

    __syncthreads();
    // C/D layout: col = lane&15 (n), row = (lane>>4)*4 + reg (c)
    #pragma unroll
    for (int mf = 0; mf < 4; mf++)
        #pragma unroll
        for (int nf = 0; nf < 4; nf++)
            #pragma unroll
            for (int r = 0; r < 4; r++) {
                int cl = mf * 16 + lg * 4 + r;
                int nl = nf * 16 + lr;
                atomicAdd(&tile[cl * 64 + nl], acc[mf][nf][r]);
            }
    __syncthreads();

    // write out: thread t handles row n_l = t>>3, cols c_l = (t&7)*8 .. +7
    int nl  = tid >> 3;
    int cl0 = (tid & 7) * 8;
    float* dst = xm + (n0 + nl) * 1024 + (c0 + cl0);
    #pragma unroll
    for (int j = 0; j < 8; j++) dst[j] = tile[(cl0 + j) * 64 + nl];
}

// ---------------- K3: pooled (xm*ym h-reduce) + FC head ----------------------
__global__ __launch_bounds__(256) void k3_head(
    const float* __restrict__ xm, const float* __restrict__ ym,
    const float* __restrict__ fcw, const float* __restrict__ fcb,
    float* __restrict__ out)
{
    __shared__ float ps[1024];
    int b = blockIdx.x, tid = threadIdx.x;
    const float inv14 = 1.0f / 14.0f;
    for (int c = tid; c < 1024; c += 256) {
        float s = 0.0f;
        #pragma unroll
        for (int h = 0; h < 14; h++)
            s += xm[(b * 16 + h) * 1024 + c] * ym[(b * 16 + h) * 1024 + c];
        ps[c] = s * inv14;
    }
    __syncthreads();
    int w = tid >> 6, l = tid & 63;
    for (int n = w; n < 30; n += 4) {
        float s = 0.0f;
        #pragma unroll
        for (int k = 0; k < 16; k++)
            s += fcw[n * 1024 + l + k * 64] * ps[l + k * 64];
        #pragma unroll
        for (int m = 32; m; m >>= 1) s += __shfl_xor(s, m, 64);
        if (l == 0) out[b * 30 + n] = s + fcb[n];
    }
}

extern "C" void kernel_launch(void* const* d_in, const int* in_sizes, int n_in,
                              void* d_out, int out_size, void* d_ws, size_t ws_size,
                              hipStream_t stream) {
    const float* f1   = (const float*)d_in[0];   // [32,2048,14,14]
    const float* f2   = (const float*)d_in[1];   // [32,1024,14,14]
    const float* cw   = (const float*)d_in[2];   // [1024,2048]
    const float* fcw  = (const float*)d_in[3];   // [30,1024]
    const float* fcb  = (const float*)d_in[4];   // [30]
    float* out = (float*)d_out;                  // [32,30]

    unsigned short* f1mt = (unsigned short*)d_ws;
    unsigned short* cwb  = (unsigned short*)((char*)d_ws + (2u << 20));
    float* ym            = (float*)((char*)d_ws + (6u << 20));
    float* xm            = (float*)((char*)d_ws + (8u << 20));

    k1_prep<<<4736, 256, 0, stream>>>(f1, f2, cw, f1mt, cwb, ym);
    k2_gemm<<<128, 512, 0, stream>>>(cwb, f1mt, xm);
    k3_head<<<32, 256, 0, stream>>>(xm, ym, fcw, fcb, out);
}

// Round 2
// 171.357 us; speedup vs baseline: 1.0630x; 1.0630x over previous
//
#include <hip/hip_runtime.h>
#include <hip/hip_bf16.h>

// B=32, C_IN=2048, C=1024, H=W=14, N_CLS=30
// pooled[b,c] = (1/14) * sum_h (conv_w @ mean_w f1)[b,c,h] * (mean_w f2)[b,c,h]
// out = pooled @ fc_w^T + fc_b
//
// ws layout:
//   [0, 2MB)       f1mt   ushort(bf16) [512][2048]  rows n = b*16+h (h padded to 16, pad rows zero)
//   [2MB, 6MB)     cwb    ushort(bf16) [1024][2048]
//   [6MB, 8MB)     ym     float [32][16][1024]      (h=14,15 rows zero)
//   [8MB, 8MB+128K) pooled float [32][1024]         (zeroed by k1, accumulated by k2 atomics)

typedef __attribute__((ext_vector_type(8))) short short8;
typedef __attribute__((ext_vector_type(4))) float f32x4;

static __device__ __forceinline__ unsigned short f2bf(float f) {
    union { float f; unsigned u; } v; v.f = f;
    return (unsigned short)((v.u + 0x7FFFu + ((v.u >> 16) & 1u)) >> 16);
}

// ---------------- K1: reductions + casts + pooled zero (memory-bound) -------
// blocks [0,256):    jobA  f1 W-reduce -> bf16 f1mt   (1 thread per (b,i) row)
// blocks [256,384):  jobB  f2 W-reduce -> f32 ym      (1 thread per (b,c) row)
// blocks [384,1408): jobC  conv_w f32 -> bf16 cast    (8 elems/thread)
// blocks [1408,1440):jobD  zero pooled                 (4 elems/thread)
__global__ __launch_bounds__(256) void k1_prep(
    const float* __restrict__ f1, const float* __restrict__ f2,
    const float* __restrict__ cw,
    unsigned short* __restrict__ f1mt, unsigned short* __restrict__ cwb,
    float* __restrict__ ym, float* __restrict__ pooled)
{
    const float inv14 = 1.0f / 14.0f;
    int blk = blockIdx.x;
    if (blk < 256) {
        int t = blk * 256 + threadIdx.x;      // 65536 threads: (b,i)
        int b = t >> 11, i = t & 2047;
        const float4* p = (const float4*)(f1 + (b * 2048 + i) * 196);
        float s[14];
        #pragma unroll
        for (int h = 0; h < 14; h++) s[h] = 0.0f;
        #pragma unroll
        for (int j = 0; j < 49; j++) {         // 784B contiguous per thread
            float4 v = p[j];
            s[(4 * j + 0) / 14] += v.x;
            s[(4 * j + 1) / 14] += v.y;
            s[(4 * j + 2) / 14] += v.z;
            s[(4 * j + 3) / 14] += v.w;
        }
        unsigned short* o = f1mt + b * 16 * 2048 + i;  // coalesced across lanes
        #pragma unroll
        for (int h = 0; h < 14; h++) o[h * 2048] = f2bf(s[h] * inv14);
        o[14 * 2048] = 0; o[15 * 2048] = 0;            // zero pad rows
    } else if (blk < 384) {
        int t = (blk - 256) * 256 + threadIdx.x;  // 32768 threads: (b,c)
        int b = t >> 10, c = t & 1023;
        const float4* p = (const float4*)(f2 + (b * 1024 + c) * 196);
        float s[14];
        #pragma unroll
        for (int h = 0; h < 14; h++) s[h] = 0.0f;
        #pragma unroll
        for (int j = 0; j < 49; j++) {
            float4 v = p[j];
            s[(4 * j + 0) / 14] += v.x;
            s[(4 * j + 1) / 14] += v.y;
            s[(4 * j + 2) / 14] += v.z;
            s[(4 * j + 3) / 14] += v.w;
        }
        float* o = ym + b * 16 * 1024 + c;
        #pragma unroll
        for (int h = 0; h < 14; h++) o[h * 1024] = s[h] * inv14;
        o[14 * 1024] = 0.0f; o[15 * 1024] = 0.0f;
    } else if (blk < 1408) {
        int t = (blk - 384) * 256 + threadIdx.x;  // 262144 threads, 8 elems each
        const float4* p = (const float4*)(cw + t * 8);
        float4 v0 = p[0], v1 = p[1];
        ushort4 a, b4;
        a.x = f2bf(v0.x); a.y = f2bf(v0.y); a.z = f2bf(v0.z); a.w = f2bf(v0.w);
        b4.x = f2bf(v1.x); b4.y = f2bf(v1.y); b4.z = f2bf(v1.z); b4.w = f2bf(v1.w);
        *(ushort4*)(cwb + t * 8)     = a;
        *(ushort4*)(cwb + t * 8 + 4) = b4;
    } else {
        int t = (blk - 1408) * 256 + threadIdx.x;  // 8192 threads, 4 elems each
        *(float4*)(pooled + t * 4) = make_float4(0.f, 0.f, 0.f, 0.f);
    }
}

// ---------------- K2: bf16 MFMA GEMM fused with ym-mul + h-reduce ------------
// M=1024 (c), N=512 (n=b*16+h), K=2048.
// 512 blocks x 4 waves = 2048 waves (2/SIMD). Wave = one 64x64 tile over a
// K-chunk of 128: tile = blockIdx>>2, kchunk = (blockIdx&3)*4 + wave.
// All 32 fragments loaded up front (32 independent 16B loads -> one drain ->
// 64 back-to-back MFMAs). Fragment k-layout: 8 CONTIGUOUS k per lane for BOTH
// A and B (shared (lane,j)->k map => any consistent k-permutation is exact).
// C/D layout (verified R1, absmax=bf16 eps): col n = lane&15, row c = (lane>>4)*4+reg.
// Fusion: within a tile, n = nf*16 + lr => h = lr (fixed per lane!), b = nt*4+nf.
// pooled_partial = sum_h acc*ym  via 16-lane __shfl_xor butterfly, then lr==0
// lanes atomicAdd 4 floats each into pooled[b][c].
__global__ __launch_bounds__(256) void k2_gemm(
    const unsigned short* __restrict__ A,   // cwb  [1024][2048]
    const unsigned short* __restrict__ Bm,  // f1mt [512][2048]
    const float* __restrict__ ym,           // [512][1024]
    float* __restrict__ pooled)             // [32][1024]
{
    int tid = threadIdx.x;
    int w  = tid >> 6;
    int l  = tid & 63;
    int lg = l >> 4;          // lane k-group
    int lr = l & 15;          // lane row/col (== h in the C fragment)
    int tile = blockIdx.x >> 2;
    int kq   = blockIdx.x & 3;
    int ct = tile >> 3, nt = tile & 7;
    int c0 = ct * 64, n0 = nt * 64;
    int kbase = (kq * 4 + w) * 128;

    const unsigned short* Ap = A  + (c0 + lr) * 2048 + kbase + lg * 8;
    const unsigned short* Bp = Bm + (n0 + lr) * 2048 + kbase + lg * 8;

    short8 af[4][4], bf[4][4];
    #pragma unroll
    for (int mf = 0; mf < 4; mf++)
        #pragma unroll
        for (int kk = 0; kk < 4; kk++)
            af[mf][kk] = *(const short8*)(Ap + mf * 16 * 2048 + kk * 32);
    #pragma unroll
    for (int nf = 0; nf < 4; nf++)
        #pragma unroll
        for (int kk = 0; kk < 4; kk++)
            bf[nf][kk] = *(const short8*)(Bp + nf * 16 * 2048 + kk * 32);

    f32x4 acc[4][4];
    #pragma unroll
    for (int mf = 0; mf < 4; mf++)
        #pragma unroll
        for (int nf = 0; nf < 4; nf++)
            acc[mf][nf] = (f32x4){0.f, 0.f, 0.f, 0.f};

    #pragma unroll
    for (int kk = 0; kk < 4; kk++)
        #pragma unroll
        for (int mf = 0; mf < 4; mf++)
            #pragma unroll
            for (int nf = 0; nf < 4; nf++)
                acc[mf][nf] = __builtin_amdgcn_mfma_f32_16x16x32_bf16(
                    af[mf][kk], bf[nf][kk], acc[mf][nf], 0, 0, 0);

    // fused epilogue: pooled[b][c] += (1/14) * sum_h xm[c][b,h] * ym[b,h][c]
    const float inv14 = 1.0f / 14.0f;
    #pragma unroll
    for (int nf = 0; nf < 4; nf++) {
        int b = nt * 4 + nf;
        const float* yrow = ym + (b * 16 + lr) * 1024 + c0 + lg * 4;  // h = lr
        #pragma unroll
        for (int mf = 0; mf < 4; mf++) {
            f32x4 yv = *(const f32x4*)(yrow + mf * 16);
            f32x4 pp = acc[mf][nf] * yv;
            #pragma unroll
            for (int st = 1; st <= 8; st <<= 1) {   // reduce over h (16 lanes)
                pp[0] += __shfl_xor(pp[0], st);
                pp[1] += __shfl_xor(pp[1], st);
                pp[2] += __shfl_xor(pp[2], st);
                pp[3] += __shfl_xor(pp[3], st);
            }
            if (lr == 0) {
                float* dst = pooled + b * 1024 + c0 + mf * 16 + lg * 4;
                atomicAdd(dst + 0, pp[0] * inv14);
                atomicAdd(dst + 1, pp[1] * inv14);
                atomicAdd(dst + 2, pp[2] * inv14);
                atomicAdd(dst + 3, pp[3] * inv14);
            }
        }
    }
}

// ---------------- K3: FC head, one wave per (b, n) dot -----------------------
__global__ __launch_bounds__(256) void k3_fc(
    const float* __restrict__ pooled, const float* __restrict__ fcw,
    const float* __restrict__ fcb, float* __restrict__ out)
{
    int g = blockIdx.x * 4 + (threadIdx.x >> 6);   // 960 waves
    int l = threadIdx.x & 63;
    int b = g / 30;
    int n = g - b * 30;
    const float4* wp = (const float4*)(fcw + n * 1024);
    const float4* pp = (const float4*)(pooled + b * 1024);
    float s = 0.0f;
    #pragma unroll
    for (int it = 0; it < 4; it++) {
        float4 wv = wp[l + it * 64];
        float4 pv = pp[l + it * 64];
        s += wv.x * pv.x + wv.y * pv.y + wv.z * pv.z + wv.w * pv.w;
    }
    #pragma unroll
    for (int m = 32; m; m >>= 1) s += __shfl_xor(s, m);
    if (l == 0) out[b * 30 + n] = s + fcb[n];
}

extern "C" void kernel_launch(void* const* d_in, const int* in_sizes, int n_in,
                              void* d_out, int out_size, void* d_ws, size_t ws_size,
                              hipStream_t stream) {
    const float* f1  = (const float*)d_in[0];   // [32,2048,14,14]
    const float* f2  = (const float*)d_in[1];   // [32,1024,14,14]
    const float* cw  = (const float*)d_in[2];   // [1024,2048]
    const float* fcw = (const float*)d_in[3];   // [30,1024]
    const float* fcb = (const float*)d_in[4];   // [30]
    float* out = (float*)d_out;                 // [32,30]

    unsigned short* f1mt = (unsigned short*)d_ws;
    unsigned short* cwb  = (unsigned short*)((char*)d_ws + (2u << 20));
    float* ym            = (float*)((char*)d_ws + (6u << 20));
    float* pooled        = (float*)((char*)d_ws + (8u << 20));

    k1_prep<<<1440, 256, 0, stream>>>(f1, f2, cw, f1mt, cwb, ym, pooled);
    k2_gemm<<<512, 256, 0, stream>>>(cwb, f1mt, ym, pooled);
    k3_fc<<<240, 256, 0, stream>>>(pooled, fcw, fcb, out);
}

// Round 7
// 136.640 us; speedup vs baseline: 1.3330x; 1.2541x over previous
//
#include <hip/hip_runtime.h>
#include <hip/hip_bf16.h>

// B=32, C_IN=2048, C=1024, H=W=14, N_CLS=30
// pooled[b,c] = (1/14) * sum_h (conv_w @ mean_w f1)[b,c,h] * (mean_w f2)[b,c,h]
// out = pooled @ fc_w^T + fc_b
//
// ws layout:
//   [0, 2MB)    f1mt        ushort(bf16) [512][2048]   rows n = b*16+h (h padded to 16, pad rows 0)
//   [2MB, 6MB)  cwb         ushort(bf16) [1024][2048]
//   [6MB, 8MB)  ym          float [32][16][1024]       (h=14,15 rows 0)
//   [8MB, 10MB) pooled_part float [16][32][1024]       (one slice per k-chunk, plain stores)

typedef __attribute__((ext_vector_type(8))) short short8;
typedef __attribute__((ext_vector_type(4))) float f32x4;

static __device__ __forceinline__ unsigned short f2bf(float f) {
    union { float f; unsigned u; } v; v.f = f;
    return (unsigned short)((v.u + 0x7FFFu + ((v.u >> 16) & 1u)) >> 16);
}

// ---------------- K1: coalesced LDS-staged reductions + cast -----------------
// blocks [0,1024):     jobA  f1 W-reduce -> bf16 f1mt   (block = one b x 64 i-rows)
// blocks [1024,1536):  jobB  f2 W-reduce -> f32 ym      (block = one b x 64 c-rows)
// blocks [1536,2560):  jobC  conv_w f32 -> bf16 cast    (8 elems/thread)
__global__ __launch_bounds__(256) void k1_prep(
    const float* __restrict__ f1, const float* __restrict__ f2,
    const float* __restrict__ cw,
    unsigned short* __restrict__ f1mt, unsigned short* __restrict__ cwb,
    float* __restrict__ ym)
{
    __shared__ float lds[64 * 196];          // 49 KB slab: 64 rows x 196 floats
    const float inv14 = 1.0f / 14.0f;
    int blk = blockIdx.x;
    int tid = threadIdx.x;

    if (blk < 1024) {
        // jobA: b = blk>>5, rows i0..i0+63 (contiguous 49KB in f1)
        int b = blk >> 5, i0 = (blk & 31) * 64;
        const float4* src = (const float4*)(f1 + (size_t)(b * 2048 + i0) * 196);
        #pragma unroll
        for (int j = 0; j < 13; j++) {        // 3136 float4, fully coalesced
            int idx = j * 256 + tid;
            if (idx < 3136) *(float4*)&lds[idx * 4] = src[idx];
        }
        __syncthreads();
        int r  = tid & 63;                    // row within slab (lane -> coalesced write)
        int hb = tid >> 6;                    // wave id
        unsigned short* o = f1mt + (size_t)b * 16 * 2048 + i0 + r;
        #pragma unroll
        for (int it = 0; it < 4; it++) {
            int h = hb + it * 4;              // 0..15
            if (h < 14) {
                const float* p = &lds[r * 196 + h * 14];
                float s = 0.0f;
                #pragma unroll
                for (int q = 0; q < 14; q++) s += p[q];
                o[h * 2048] = f2bf(s * inv14);
            } else {
                o[h * 2048] = 0;              // pad rows 14,15
            }
        }
    } else if (blk < 1536) {
        // jobB: 16 blocks per b, 64 c-rows each
        int t = blk - 1024;
        int b = t >> 4, c0 = (t & 15) * 64;
        const float4* src = (const float4*)(f2 + (size_t)(b * 1024 + c0) * 196);
        #pragma unroll
        for (int j = 0; j < 13; j++) {
            int idx = j * 256 + tid;
            if (idx < 3136) *(float4*)&lds[idx * 4] = src[idx];
        }
        __syncthreads();
        int r  = tid & 63;
        int hb = tid >> 6;
        float* o = ym + (size_t)b * 16 * 1024 + c0 + r;
        #pragma unroll
        for (int it = 0; it < 4; it++) {
            int h = hb + it * 4;
            if (h < 14) {
                const float* p = &lds[r * 196 + h * 14];
                float s = 0.0f;
                #pragma unroll
                for (int q = 0; q < 14; q++) s += p[q];
                o[h * 1024] = s * inv14;
            } else {
                o[h * 1024] = 0.0f;
            }
        }
    } else {
        // jobC: cast conv_w (2M elems) to bf16, 8 per thread
        int t = (blk - 1536) * 256 + tid;
        const float4* p = (const float4*)(cw + (size_t)t * 8);
        float4 v0 = p[0], v1 = p[1];
        ushort4 a, b4;
        a.x = f2bf(v0.x); a.y = f2bf(v0.y); a.z = f2bf(v0.z); a.w = f2bf(v0.w);
        b4.x = f2bf(v1.x); b4.y = f2bf(v1.y); b4.z = f2bf(v1.z); b4.w = f2bf(v1.w);
        *(ushort4*)(cwb + (size_t)t * 8)     = a;
        *(ushort4*)(cwb + (size_t)t * 8 + 4) = b4;
    }
}

// ---------------- K2: bf16 MFMA GEMM fused with ym-mul + h-reduce ------------
// M=1024 (c), N=512 (n=b*16+h), K=2048.
// 512 blocks x 4 waves = 2048 waves. Wave = one 64x64 tile over a K-chunk of
// 128: tile = blockIdx>>2, kchunk = (blockIdx&3)*4 + wave.
// All 32 fragments loaded up front (32 independent 16B loads -> one drain ->
// 64 back-to-back MFMAs). Fragment k-layout: 8 CONTIGUOUS k per lane for BOTH
// A and B (shared (lane,j)->k map => any consistent k-permutation is exact).
// C/D layout (verified R1/R2): col n = lane&15, row c = (lane>>4)*4+reg.
// Fusion: n = nf*16 + lr => h = lr (fixed per lane), b = nt*4+nf.
// Partial pooled written non-atomically to pooled_part[kchunk][b][c] as
// per-lane float4 stores (lr==0 lanes, 64B contiguous per mf).
__global__ __launch_bounds__(256) void k2_gemm(
    const unsigned short* __restrict__ A,   // cwb  [1024][2048]
    const unsigned short* __restrict__ Bm,  // f1mt [512][2048]
    const float* __restrict__ ym,           // [512][1024]
    float* __restrict__ part)               // [16][32][1024]
{
    int tid = threadIdx.x;
    int w  = tid >> 6;
    int l  = tid & 63;
    int lg = l >> 4;          // lane k-group
    int lr = l & 15;          // lane row/col (== h in the C fragment)
    int tile = blockIdx.x >> 2;
    int kq   = blockIdx.x & 3;
    int ct = tile >> 3, nt = tile & 7;
    int c0 = ct * 64, n0 = nt * 64;
    int kc = kq * 4 + w;      // k-chunk id 0..15
    int kbase = kc * 128;

    const unsigned short* Ap = A  + (size_t)(c0 + lr) * 2048 + kbase + lg * 8;
    const unsigned short* Bp = Bm + (size_t)(n0 + lr) * 2048 + kbase + lg * 8;

    short8 af[4][4], bf[4][4];
    #pragma unroll
    for (int mf = 0; mf < 4; mf++)
        #pragma unroll
        for (int kk = 0; kk < 4; kk++)
            af[mf][kk] = *(const short8*)(Ap + mf * 16 * 2048 + kk * 32);
    #pragma unroll
    for (int nf = 0; nf < 4; nf++)
        #pragma unroll
        for (int kk = 0; kk < 4; kk++)
            bf[nf][kk] = *(const short8*)(Bp + nf * 16 * 2048 + kk * 32);

    f32x4 acc[4][4];
    #pragma unroll
    for (int mf = 0; mf < 4; mf++)
        #pragma unroll
        for (int nf = 0; nf < 4; nf++)
            acc[mf][nf] = (f32x4){0.f, 0.f, 0.f, 0.f};

    #pragma unroll
    for (int kk = 0; kk < 4; kk++)
        #pragma unroll
        for (int mf = 0; mf < 4; mf++)
            #pragma unroll
            for (int nf = 0; nf < 4; nf++)
                acc[mf][nf] = __builtin_amdgcn_mfma_f32_16x16x32_bf16(
                    af[mf][kk], bf[nf][kk], acc[mf][nf], 0, 0, 0);

    // fused epilogue: part[kc][b][c] = (1/14) * sum_h xm_partial * ym
    const float inv14 = 1.0f / 14.0f;
    #pragma unroll
    for (int nf = 0; nf < 4; nf++) {
        int b = nt * 4 + nf;
        const float* yrow = ym + (size_t)(b * 16 + lr) * 1024 + c0 + lg * 4;  // h = lr
        #pragma unroll
        for (int mf = 0; mf < 4; mf++) {
            f32x4 yv = *(const f32x4*)(yrow + mf * 16);
            f32x4 pp = acc[mf][nf] * yv;
            #pragma unroll
            for (int st = 1; st <= 8; st <<= 1) {   // reduce over h (16 lanes)
                pp[0] += __shfl_xor(pp[0], st);
                pp[1] += __shfl_xor(pp[1], st);
                pp[2] += __shfl_xor(pp[2], st);
                pp[3] += __shfl_xor(pp[3], st);
            }
            if (lr == 0) {
                float* dst = part + (size_t)kc * 32768 + b * 1024 + c0 + mf * 16 + lg * 4;
                *(f32x4*)dst = pp * inv14;          // 4 lanes x 16B = 64B contiguous
            }
        }
    }
}

// ---------------- K3: reduce 16 k-partials + FC head (one block per b) -------
__global__ __launch_bounds__(256) void k3_fc(
    const float* __restrict__ part, const float* __restrict__ fcw,
    const float* __restrict__ fcb, float* __restrict__ out)
{
    __shared__ float ps[1024];
    int b = blockIdx.x, tid = threadIdx.x;
    #pragma unroll
    for (int c = tid; c < 1024; c += 256) {
        float s = 0.0f;
        #pragma unroll
        for (int k = 0; k < 16; k++)
            s += part[(size_t)k * 32768 + b * 1024 + c];
        ps[c] = s;
    }
    __syncthreads();
    int w = tid >> 6, l = tid & 63;
    const float4* pp = (const float4*)ps;
    for (int n = w; n < 30; n += 4) {
        const float4* wp = (const float4*)(fcw + n * 1024);
        float s = 0.0f;
        #pragma unroll
        for (int it = 0; it < 4; it++) {
            float4 wv = wp[l + it * 64];
            float4 pv = pp[l + it * 64];
            s += wv.x * pv.x + wv.y * pv.y + wv.z * pv.z + wv.w * pv.w;
        }
        #pragma unroll
        for (int m = 32; m; m >>= 1) s += __shfl_xor(s, m);
        if (l == 0) out[b * 30 + n] = s + fcb[n];
    }
}

extern "C" void kernel_launch(void* const* d_in, const int* in_sizes, int n_in,
                              void* d_out, int out_size, void* d_ws, size_t ws_size,
                              hipStream_t stream) {
    const float* f1  = (const float*)d_in[0];   // [32,2048,14,14]
    const float* f2  = (const float*)d_in[1];   // [32,1024,14,14]
    const float* cw  = (const float*)d_in[2];   // [1024,2048]
    const float* fcw = (const float*)d_in[3];   // [30,1024]
    const float* fcb = (const float*)d_in[4];   // [30]
    float* out = (float*)d_out;                 // [32,30]

    unsigned short* f1mt = (unsigned short*)d_ws;
    unsigned short* cwb  = (unsigned short*)((char*)d_ws + (2u << 20));
    float* ym            = (float*)((char*)d_ws + (6u << 20));
    float* part          = (float*)((char*)d_ws + (8u << 20));

    k1_prep<<<2560, 256, 0, stream>>>(f1, f2, cw, f1mt, cwb, ym);
    k2_gemm<<<512, 256, 0, stream>>>(cwb, f1mt, ym, part);
    k3_fc<<<32, 256, 0, stream>>>(part, fcw, fcb, out);
}

// Round 10
// 133.937 us; speedup vs baseline: 1.3599x; 1.0202x over previous
//
#include <hip/hip_runtime.h>
#include <hip/hip_bf16.h>

// B=32, C_IN=2048, C=1024, H=W=14, N_CLS=30
// pooled[b,c] = (1/14) * sum_h (conv_w @ mean_w f1)[b,c,h] * (mean_w f2)[b,c,h]
// out = pooled @ fc_w^T + fc_b
//
// ws layout:
//   [0, 2MB)    f1mt  ushort(bf16) [512][2048]   rows n = b*16+h (h padded to 16, pad rows 0)
//   [2MB, 6MB)  cwb   ushort(bf16) [1024][2048]
//   [6MB, 8MB)  ym    float [32][16][1024]       (h=14,15 rows 0)
//   [8MB, 10MB) part  float [16][32][1024]       (one slice per k-chunk, plain stores)

typedef __attribute__((ext_vector_type(8))) short short8;
typedef __attribute__((ext_vector_type(4))) float f32x4;

static __device__ __forceinline__ unsigned short f2bf(float f) {
    union { float f; unsigned u; } v; v.f = f;
    return (unsigned short)((v.u + 0x7FFFu + ((v.u >> 16) & 1u)) >> 16);
}

#define LROW 197   // LDS row stride in floats: gcd(197,32)=1 -> conflict-free reduce

// ---------------- K1: coalesced LDS-staged reductions + cast -----------------
// blocks [0,1024):     jobA  f1 W-reduce -> bf16 f1mt   (block = one b x 64 i-rows)
// blocks [1024,1536):  jobB  f2 W-reduce -> f32 ym      (block = one b x 64 c-rows)
// blocks [1536,2560):  jobC  conv_w f32 -> bf16 cast    (8 elems/thread)
__global__ __launch_bounds__(256) void k1_prep(
    const float* __restrict__ f1, const float* __restrict__ f2,
    const float* __restrict__ cw,
    unsigned short* __restrict__ f1mt, unsigned short* __restrict__ cwb,
    float* __restrict__ ym)
{
    __shared__ float lds[64 * LROW];         // 50.4 KB: 64 rows x 197 floats
    const float inv14 = 1.0f / 14.0f;
    int blk = blockIdx.x;
    int tid = threadIdx.x;

    if (blk < 1024) {
        // jobA: b = blk>>5, rows i0..i0+63 (contiguous 49KB in f1)
        int b = blk >> 5, i0 = (blk & 31) * 64;
        const float4* src = (const float4*)(f1 + (size_t)(b * 2048 + i0) * 196);
        #pragma unroll
        for (int j = 0; j < 13; j++) {        // 3136 float4, fully coalesced reads
            unsigned idx = j * 256 + tid;
            if (idx < 3136) {
                unsigned row = idx / 49, col = idx - row * 49;
                *(float4*)&lds[row * LROW + col * 4] = src[idx];
            }
        }
        __syncthreads();
        int r  = tid & 63;                    // row within slab (lane -> coalesced write)
        int hb = tid >> 6;                    // wave id
        unsigned short* o = f1mt + (size_t)b * 16 * 2048 + i0 + r;
        #pragma unroll
        for (int it = 0; it < 4; it++) {
            int h = hb + it * 4;              // 0..15
            if (h < 14) {
                const float* p = &lds[r * LROW + h * 14];
                float s = 0.0f;
                #pragma unroll
                for (int q = 0; q < 14; q++) s += p[q];
                o[h * 2048] = f2bf(s * inv14);
            } else {
                o[h * 2048] = 0;              // pad rows 14,15
            }
        }
    } else if (blk < 1536) {
        // jobB: 16 blocks per b, 64 c-rows each
        int t = blk - 1024;
        int b = t >> 4, c0 = (t & 15) * 64;
        const float4* src = (const float4*)(f2 + (size_t)(b * 1024 + c0) * 196);
        #pragma unroll
        for (int j = 0; j < 13; j++) {
            unsigned idx = j * 256 + tid;
            if (idx < 3136) {
                unsigned row = idx / 49, col = idx - row * 49;
                *(float4*)&lds[row * LROW + col * 4] = src[idx];
            }
        }
        __syncthreads();
        int r  = tid & 63;
        int hb = tid >> 6;
        float* o = ym + (size_t)b * 16 * 1024 + c0 + r;
        #pragma unroll
        for (int it = 0; it < 4; it++) {
            int h = hb + it * 4;
            if (h < 14) {
                const float* p = &lds[r * LROW + h * 14];
                float s = 0.0f;
                #pragma unroll
                for (int q = 0; q < 14; q++) s += p[q];
                o[h * 1024] = s * inv14;
            } else {
                o[h * 1024] = 0.0f;
            }
        }
    } else {
        // jobC: cast conv_w (2M elems) to bf16, 8 per thread
        int t = (blk - 1536) * 256 + tid;
        const float4* p = (const float4*)(cw + (size_t)t * 8);
        float4 v0 = p[0], v1 = p[1];
        ushort4 a, b4;
        a.x = f2bf(v0.x); a.y = f2bf(v0.y); a.z = f2bf(v0.z); a.w = f2bf(v0.w);
        b4.x = f2bf(v1.x); b4.y = f2bf(v1.y); b4.z = f2bf(v1.z); b4.w = f2bf(v1.w);
        *(ushort4*)(cwb + (size_t)t * 8)     = a;
        *(ushort4*)(cwb + (size_t)t * 8 + 4) = b4;
    }
}

// ---------------- K2: bf16 MFMA GEMM fused with ym-mul + h-reduce ------------
// M=1024 (c), N=512 (n=b*16+h), K=2048. Tile 64x32 x K-chunk 512 per block.
// 1024 blocks x 4 waves = 4096 waves (16/CU). Wave = 64x32 tile x K=128.
// XCD swizzle (nwg=1024 % 8 == 0, bijective): 128 consecutive sids per XCD
// = 2 A-panels (512KB) + f1mt (2MB) + ym (2MB) ~ 4.5MB -> per-XCD L2 resident.
// Fragment pipeline: 2 halves (unroll 1) x {12 loads, 16 MFMA} -> ~12 frag
// regs live (48 VGPR) + 32 acc, no spills, 12 loads of MLP per wave.
// Fragment k-layout: 8 CONTIGUOUS k per lane for BOTH A and B (shared
// (lane,j)->k map => any consistent k-permutation is exact).
// C/D layout (verified R1/R2): col n = lane&15, row c = (lane>>4)*4+reg.
// Fusion: n = nf*16 + lr => h = lr (fixed per lane), b = nt*2+nf.
// Partials written non-atomically to part[kc][b][c] (float4, 64B contiguous).
__global__ __launch_bounds__(256) void k2_gemm(
    const unsigned short* __restrict__ A,   // cwb  [1024][2048]
    const unsigned short* __restrict__ Bm,  // f1mt [512][2048]
    const float* __restrict__ ym,           // [512][1024]
    float* __restrict__ part)               // [16][32][1024]
{
    int tid = threadIdx.x;
    int w  = tid >> 6;
    int l  = tid & 63;
    int lg = l >> 4;          // lane k-group
    int lr = l & 15;          // lane row/col (== h in the C fragment)

    int bid = blockIdx.x;
    int sid = (bid & 7) * 128 + (bid >> 3);   // XCD-contiguous remap (bijective)
    int ct  = sid >> 6;          // 0..15  -> c0
    int rem = sid & 63;
    int nt  = rem >> 2;          // 0..15  -> n0
    int kq  = rem & 3;           // 0..3
    int c0 = ct * 64, n0 = nt * 32;
    int kc = kq * 4 + w;         // k-chunk id 0..15
    int kbase = kc * 128;

    const unsigned short* Ap = A  + (size_t)(c0 + lr) * 2048 + kbase + lg * 8;
    const unsigned short* Bp = Bm + (size_t)(n0 + lr) * 2048 + kbase + lg * 8;

    f32x4 acc[4][2];
    #pragma unroll
    for (int mf = 0; mf < 4; mf++)
        #pragma unroll
        for (int nf = 0; nf < 2; nf++)
            acc[mf][nf] = (f32x4){0.f, 0.f, 0.f, 0.f};

    #pragma unroll 1
    for (int half = 0; half < 2; half++) {   // not unrolled: caps frag pressure
        short8 af[4][2], bf[2][2];
        #pragma unroll
        for (int kk = 0; kk < 2; kk++) {
            int ko = half * 64 + kk * 32;
            #pragma unroll
            for (int mf = 0; mf < 4; mf++)
                af[mf][kk] = *(const short8*)(Ap + mf * 16 * 2048 + ko);
            #pragma unroll
            for (int nf = 0; nf < 2; nf++)
                bf[nf][kk] = *(const short8*)(Bp + nf * 16 * 2048 + ko);
        }
        #pragma unroll
        for (int kk = 0; kk < 2; kk++)
            #pragma unroll
            for (int mf = 0; mf < 4; mf++)
                #pragma unroll
                for (int nf = 0; nf < 2; nf++)
                    acc[mf][nf] = __builtin_amdgcn_mfma_f32_16x16x32_bf16(
                        af[mf][kk], bf[nf][kk], acc[mf][nf], 0, 0, 0);
    }

    // fused epilogue: part[kc][b][c] = (1/14) * sum_h xm_partial * ym
    const float inv14 = 1.0f / 14.0f;
    #pragma unroll
    for (int nf = 0; nf < 2; nf++) {
        int b = nt * 2 + nf;
        const float* yrow = ym + (size_t)(b * 16 + lr) * 1024 + c0 + lg * 4;  // h = lr
        #pragma unroll
        for (int mf = 0; mf < 4; mf++) {
            f32x4 yv = *(const f32x4*)(yrow + mf * 16);
            f32x4 pp = acc[mf][nf] * yv;
            #pragma unroll
            for (int st = 1; st <= 8; st <<= 1) {   // reduce over h (16 lanes)
                pp[0] += __shfl_xor(pp[0], st);
                pp[1] += __shfl_xor(pp[1], st);
                pp[2] += __shfl_xor(pp[2], st);
                pp[3] += __shfl_xor(pp[3], st);
            }
            if (lr == 0) {
                float* dst = part + (size_t)kc * 32768 + b * 1024 + c0 + mf * 16 + lg * 4;
                *(f32x4*)dst = pp * inv14;          // 4 lanes x 16B = 64B contiguous
            }
        }
    }
}

// ---------------- K3: reduce 16 k-partials + FC head (one block per b) -------
__global__ __launch_bounds__(1024) void k3_fc(
    const float* __restrict__ part, const float* __restrict__ fcw,
    const float* __restrict__ fcb, float* __restrict__ out)
{
    __shared__ float ps[1024];
    int b = blockIdx.x, tid = threadIdx.x;
    float s = 0.0f;
    #pragma unroll
    for (int k = 0; k < 16; k++)
        s += part[(size_t)k * 32768 + b * 1024 + tid];
    ps[tid] = s;
    __syncthreads();
    int w = tid >> 6, l = tid & 63;
    for (int n = w; n < 30; n += 16) {
        const float* wp = fcw + n * 1024;
        float t = 0.0f;
        #pragma unroll
        for (int it = 0; it < 16; it++)
            t += wp[l + it * 64] * ps[l + it * 64];   // scalar: 2-way LDS, free
        #pragma unroll
        for (int m = 32; m; m >>= 1) t += __shfl_xor(t, m);
        if (l == 0) out[b * 30 + n] = t + fcb[n];
    }
}

extern "C" void kernel_launch(void* const* d_in, const int* in_sizes, int n_in,
                              void* d_out, int out_size, void* d_ws, size_t ws_size,
                              hipStream_t stream) {
    const float* f1  = (const float*)d_in[0];   // [32,2048,14,14]
    const float* f2  = (const float*)d_in[1];   // [32,1024,14,14]
    const float* cw  = (const float*)d_in[2];   // [1024,2048]
    const float* fcw = (const float*)d_in[3];   // [30,1024]
    const float* fcb = (const float*)d_in[4];   // [30]
    float* out = (float*)d_out;                 // [32,30]

    unsigned short* f1mt = (unsigned short*)d_ws;
    unsigned short* cwb  = (unsigned short*)((char*)d_ws + (2u << 20));
    float* ym            = (float*)((char*)d_ws + (6u << 20));
    float* part          = (float*)((char*)d_ws + (8u << 20));

    k1_prep<<<2560, 256, 0, stream>>>(f1, f2, cw, f1mt, cwb, ym);
    k2_gemm<<<1024, 256, 0, stream>>>(cwb, f1mt, ym, part);
    k3_fc<<<32, 1024, 0, stream>>>(part, fcw, fcb, out);
}